// Round 6
// baseline (958.872 us; speedup 1.0000x reference)
//
#include <hip/hip_runtime.h>
#include <hip/hip_bf16.h>

// GAT: 3 layers. N=50000 nodes, E=800000 edges, H=4 heads.
// R6: streaming MFMA GEMMs — producers emit bf16 hi/lo row-major, GEMM has
// no LDS/barriers/cvt: 16 coalesced frag loads + 48 MFMAs per chunk with
// 1-deep register prefetch. Workspace kept at ~262.5 MB via slot reuse.

#define NN 50000
#define NE 800000
#define NH_HEADS 4

typedef __attribute__((ext_vector_type(8))) short short8;
typedef __attribute__((ext_vector_type(4))) float floatx4;

__device__ inline float bf2f(short s) {
    union { unsigned u; float f; } v; v.u = ((unsigned)(unsigned short)s) << 16;
    return v.f;
}
__device__ inline short f2bf_rne(float x) {
    union { float f; unsigned u; } v; v.f = x;
    unsigned r = v.u + 0x7fff + ((v.u >> 16) & 1);
    return (short)(r >> 16);
}
// truncation hi/lo split: hi = trunc16(x), lo = trunc16(x - hi)
__device__ inline void split1(float x, short& h, short& l) {
    union { float f; unsigned u; } v; v.f = x;
    h = (short)(v.u >> 16);
    union { float f; unsigned u; } rv; rv.f = v.f - bf2f(h);
    l = (short)(rv.u >> 16);
}

// ---------------- CSR build ----------------

__global__ void hist_kernel(const int* __restrict__ dst, int* __restrict__ deg, int E) {
    int e = blockIdx.x * 256 + threadIdx.x;
    if (e < E) atomicAdd(&deg[dst[e]], 1);
}

__global__ void scan_block_kernel(const int* __restrict__ deg, int* __restrict__ offs,
                                  int* __restrict__ bsums, int n) {
    __shared__ int s[256];
    int tid = threadIdx.x;
    int i = blockIdx.x * 256 + tid;
    int v = (i < n) ? deg[i] : 0;
    s[tid] = v;
    __syncthreads();
    for (int off = 1; off < 256; off <<= 1) {
        int x = (tid >= off) ? s[tid - off] : 0;
        __syncthreads();
        s[tid] += x;
        __syncthreads();
    }
    if (i < n) offs[i] = s[tid] - v;
    if (tid == 255) bsums[blockIdx.x] = s[255];
}

__global__ void scan_sums_kernel(const int* __restrict__ bsums, int* __restrict__ boffs, int nb) {
    __shared__ int s[256];
    int tid = threadIdx.x;
    int v = (tid < nb) ? bsums[tid] : 0;
    s[tid] = v;
    __syncthreads();
    for (int off = 1; off < 256; off <<= 1) {
        int x = (tid >= off) ? s[tid - off] : 0;
        __syncthreads();
        s[tid] += x;
        __syncthreads();
    }
    boffs[tid] = s[tid] - v;
}

__global__ void add_offs_kernel(int* __restrict__ offs, const int* __restrict__ boffs,
                                int* __restrict__ cursor, int n, int total) {
    int i = blockIdx.x * 256 + threadIdx.x;
    if (i < n) {
        int o = offs[i] + boffs[blockIdx.x];
        offs[i] = o;
        cursor[i] = o;
    }
    if (i == 0) offs[n] = total;
}

__global__ void scatter_kernel(const int* __restrict__ src, const int* __restrict__ dst,
                               int* __restrict__ cursor, int* __restrict__ psrc, int E) {
    int e = blockIdx.x * 256 + threadIdx.x;
    if (e < E) {
        int p = atomicAdd(&cursor[dst[e]], 1);
        psrc[p] = src[e];
    }
}

// ---------------- A (row-major fp32) -> row-major bf16 hi/lo ----------------

__global__ __launch_bounds__(256) void splitA_rm(const float* __restrict__ A,
                                                 short* __restrict__ hi,
                                                 short* __restrict__ lo,
                                                 int total8) {
    int tid = blockIdx.x * 256 + threadIdx.x;
    if (tid >= total8) return;
    const float* p = A + (size_t)tid * 8;
    float4 x0 = ((const float4*)p)[0];
    float4 x1 = ((const float4*)p)[1];
    float xs[8] = {x0.x, x0.y, x0.z, x0.w, x1.x, x1.y, x1.z, x1.w};
    short8 hv, lv;
#pragma unroll
    for (int j = 0; j < 8; ++j) { short h, l; split1(xs[j], h, l); hv[j] = h; lv[j] = l; }
    ((short8*)hi)[tid] = hv;
    ((short8*)lo)[tid] = lv;
}

// ---------------- B -> bf16 hi/lo in MFMA B-fragment order ----------------
// offset (short8) = (c*(N/16)+g)*64 + lane ; lane=(n&15)+16*((k&31)>>3), j=k&7

__global__ __launch_bounds__(256) void splitB_kernel(const float* __restrict__ B,
                                                     short* __restrict__ hi,
                                                     short* __restrict__ lo,
                                                     int K, int N) {
    int tid = blockIdx.x * 256 + threadIdx.x;
    int NG = N >> 4;
    int total = (K >> 5) * NG * 64;
    if (tid >= total) return;
    int lane = tid & 63;
    int rc = tid >> 6;
    int g = rc % NG, c = rc / NG;
    int n = g * 16 + (lane & 15);
    int k = c * 32 + (lane >> 4) * 8;
    short8 hv, lv;
#pragma unroll
    for (int j = 0; j < 8; ++j) {
        float x = B[(size_t)(k + j) * N + n];
        short h = f2bf_rne(x);
        hv[j] = h;
        lv[j] = f2bf_rne(x - bf2f(h));
    }
    ((short8*)hi)[tid] = hv;
    ((short8*)lo)[tid] = lv;
}

// permuted-W2: Bp[h*256+k, c] = W2[k, h*256+c]; K=1024, N=256
__global__ __launch_bounds__(256) void splitB2_kernel(const float* __restrict__ W2,
                                                      short* __restrict__ hi,
                                                      short* __restrict__ lo) {
    int tid = blockIdx.x * 256 + threadIdx.x;
    const int NG = 16;
    int total = (1024 >> 5) * NG * 64;   // 32768
    if (tid >= total) return;
    int lane = tid & 63;
    int rc = tid >> 6;
    int g = rc % NG, c = rc / NG;
    int n = g * 16 + (lane & 15);
    int kk = c * 32 + (lane >> 4) * 8;
    short8 hv, lv;
#pragma unroll
    for (int j = 0; j < 8; ++j) {
        int kg = kk + j;
        int h = kg >> 8, k = kg & 255;
        float x = W2[(size_t)k * 1024 + h * 256 + n];
        short hb = f2bf_rne(x);
        hv[j] = hb;
        lv[j] = f2bf_rne(x - bf2f(hb));
    }
    ((short8*)hi)[tid] = hv;
    ((short8*)lo)[tid] = lv;
}

// ---------------- streaming MFMA GEMM, N=256 fixed ----------------
// block: 64 rows x 256 cols; wave w owns rows [bm,bm+64) x cols [w*64,(w+1)*64).
// A row-major bf16 hi/lo; B frag-order. No LDS, no barriers, 1-deep prefetch.

__device__ inline floatx4 mfma16(short8 a, short8 b, floatx4 c) {
    return __builtin_amdgcn_mfma_f32_16x16x32_bf16(a, b, c, 0, 0, 0);
}

__global__ __launch_bounds__(256) void gemm_n256s(const short* __restrict__ Ahi,
                                                  const short* __restrict__ Alo,
                                                  const short* __restrict__ Bh,
                                                  const short* __restrict__ Bl,
                                                  const float* __restrict__ bias4,
                                                  float* __restrict__ C,
                                                  int M, int K) {
    int KC = K >> 5;
    int t = threadIdx.x;
    int lane = t & 63;
    int w = t >> 6;
    int bm = blockIdx.x * 64;
    int g0 = w * 4;
    const short8* pBh = (const short8*)Bh;
    const short8* pBl = (const short8*)Bl;

    floatx4 acc[4][4] = {};

    size_t abase[4];
#pragma unroll
    for (int mt = 0; mt < 4; ++mt) {
        int row = bm + mt * 16 + (lane & 15);
        if (row >= M) row = M - 1;            // clamp: finite garbage, never stored
        abase[mt] = (size_t)row * K + ((lane >> 4) << 3);
    }

    short8 ah[4], al[4], bh[4], bl[4];
#pragma unroll
    for (int mt = 0; mt < 4; ++mt) {
        ah[mt] = *(const short8*)(Ahi + abase[mt]);
        al[mt] = *(const short8*)(Alo + abase[mt]);
    }
#pragma unroll
    for (int g = 0; g < 4; ++g) {
        bh[g] = pBh[(size_t)(g0 + g) * 64 + lane];
        bl[g] = pBl[(size_t)(g0 + g) * 64 + lane];
    }

    for (int c = 0; c < KC; ++c) {
        int cn = (c + 1 < KC) ? (c + 1) : c;
        short8 ahn[4], aln[4], bhn[4], bln[4];
#pragma unroll
        for (int mt = 0; mt < 4; ++mt) {
            ahn[mt] = *(const short8*)(Ahi + abase[mt] + cn * 32);
            aln[mt] = *(const short8*)(Alo + abase[mt] + cn * 32);
        }
#pragma unroll
        for (int g = 0; g < 4; ++g) {
            bhn[g] = pBh[((size_t)cn * 16 + g0 + g) * 64 + lane];
            bln[g] = pBl[((size_t)cn * 16 + g0 + g) * 64 + lane];
        }
#pragma unroll
        for (int mt = 0; mt < 4; ++mt)
#pragma unroll
            for (int g = 0; g < 4; ++g) {
                acc[mt][g] = mfma16(ah[mt], bh[g], acc[mt][g]);
                acc[mt][g] = mfma16(al[mt], bh[g], acc[mt][g]);
                acc[mt][g] = mfma16(ah[mt], bl[g], acc[mt][g]);
            }
#pragma unroll
        for (int mt = 0; mt < 4; ++mt) { ah[mt] = ahn[mt]; al[mt] = aln[mt]; }
#pragma unroll
        for (int g = 0; g < 4; ++g) { bh[g] = bhn[g]; bl[g] = bln[g]; }
    }

    // C/D layout: col = lane&15, row = (lane>>4)*4 + reg
    int rowb = bm + (lane >> 4) * 4;
    int colb = w * 64 + (lane & 15);
#pragma unroll
    for (int mt = 0; mt < 4; ++mt) {
#pragma unroll
        for (int r = 0; r < 4; ++r) {
            int row = rowb + mt * 16 + r;
            if (row < M) {
#pragma unroll
                for (int g = 0; g < 4; ++g) {
                    int col = colb + g * 16;
                    float v = acc[mt][g][r];
                    if (bias4) {
                        v = 0.25f * (v + bias4[col] + bias4[col + 256] +
                                     bias4[col + 512] + bias4[col + 768]);
                    }
                    C[(size_t)row * 256 + col] = v;
                }
            }
        }
    }
}

// ---------------- attention score parts ----------------

__global__ __launch_bounds__(256) void elr_kernel(const float* __restrict__ z,
                                                  const float* __restrict__ al,
                                                  const float* __restrict__ ar,
                                                  float* __restrict__ el,
                                                  float* __restrict__ er,
                                                  int NH, int F) {
    int gid = blockIdx.x * 256 + threadIdx.x;
    int w = gid >> 6;
    int lane = threadIdx.x & 63;
    if (w >= NH) return;
    int n = w >> 2, h = w & 3;
    const float* zr = z + (size_t)n * (4 * F) + h * F;
    const float* alr = al + h * F;
    const float* arr = ar + h * F;
    float se = 0.f, sr = 0.f;
    for (int f = lane; f < F; f += 64) {
        float zv = zr[f];
        se += zv * alr[f];
        sr += zv * arr[f];
    }
#pragma unroll
    for (int off = 32; off > 0; off >>= 1) {
        se += __shfl_down(se, off);
        sr += __shfl_down(sr, off);
    }
    if (lane == 0) { el[w] = se; er[w] = sr; }
}

// val[h*256+k] = sum_j W2[k,h*256+j]*al2[h,j] ; var likewise with ar2
__global__ __launch_bounds__(256) void proj_av_kernel(const float* __restrict__ W2,
                                                      const float* __restrict__ al2,
                                                      const float* __restrict__ ar2,
                                                      float* __restrict__ val,
                                                      float* __restrict__ var_) {
    int gid = blockIdx.x * 256 + threadIdx.x;
    int w = gid >> 6;
    int lane = threadIdx.x & 63;
    if (w >= 1024) return;
    int h = w >> 8, k = w & 255;
    const float* wrow = W2 + (size_t)k * 1024 + h * 256;
    const float* ap = al2 + h * 256;
    const float* rp = ar2 + h * 256;
    float sv = 0.f, sr = 0.f;
    for (int j = lane; j < 256; j += 64) {
        float x = wrow[j];
        sv += x * ap[j];
        sr += x * rp[j];
    }
#pragma unroll
    for (int off = 32; off > 0; off >>= 1) {
        sv += __shfl_down(sv, off);
        sr += __shfl_down(sr, off);
    }
    if (lane == 0) { val[w] = sv; var_[w] = sr; }
}

// el[n,h] = h1[n,:]·val[h,:], er likewise
__global__ __launch_bounds__(256) void elr2_kernel(const float* __restrict__ h1,
                                                   const float* __restrict__ val,
                                                   const float* __restrict__ var_,
                                                   float* __restrict__ el,
                                                   float* __restrict__ er) {
    int gid = blockIdx.x * 256 + threadIdx.x;
    int w = gid >> 6;
    int lane = threadIdx.x & 63;
    if (w >= NN * 4) return;
    int n = w >> 2, h = w & 3;
    const float* hr = h1 + (size_t)n * 256;
    const float* vp = val + h * 256;
    const float* rp = var_ + h * 256;
    float se = 0.f, sr = 0.f;
    for (int k = lane; k < 256; k += 64) {
        float x = hr[k];
        se += x * vp[k];
        sr += x * rp[k];
    }
#pragma unroll
    for (int off = 32; off > 0; off >>= 1) {
        se += __shfl_down(se, off);
        sr += __shfl_down(sr, off);
    }
    if (lane == 0) { el[w] = se; er[w] = sr; }
}

// ---------------- aggregation ----------------
// layer 0: elu epilogue, writes bf16 hi/lo row-major (consumed only by L1 GEMM)

__global__ __launch_bounds__(256) void agg_bf_kernel(const float* __restrict__ z,
                                                     const float* __restrict__ el,
                                                     const float* __restrict__ er,
                                                     const int* __restrict__ offs,
                                                     const int* __restrict__ psrc,
                                                     const float* __restrict__ bias,
                                                     short* __restrict__ ohi,
                                                     short* __restrict__ olo) {
    int n = blockIdx.x;
    int t = threadIdx.x;
    int h = t >> 6;
    __shared__ float p_lds[64][4];
    __shared__ int src_lds[64];
    __shared__ float den_lds[4];
    if (t < 4) den_lds[t] = 0.f;
    int beg = offs[n], end = offs[n + 1];
    float acc = 0.f;
    int e_local = t >> 2, hh = t & 3;
    float er_n = er[n * 4 + hh];
    for (int base = beg; base < end; base += 64) {
        int cnt = min(64, end - base);
        __syncthreads();
        if (e_local < cnt) {
            int s = psrc[base + e_local];
            if (hh == 0) src_lds[e_local] = s;
            float sc = el[s * 4 + hh] + er_n;
            sc = (sc > 0.f) ? sc : 0.2f * sc;
            float p = __expf(sc);
            p_lds[e_local][hh] = p;
            atomicAdd(&den_lds[hh], p);
        }
        __syncthreads();
        for (int e = 0; e < cnt; ++e) {
            acc += p_lds[e][h] * z[(size_t)src_lds[e] * 256 + t];
        }
    }
    __syncthreads();
    float o = acc / fmaxf(den_lds[h], 1e-9f) + bias[t];
    o = (o > 0.f) ? o : (__expf(o) - 1.f);
    short hv, lv;
    split1(o, hv, lv);
    ohi[(size_t)n * 256 + t] = hv;
    olo[(size_t)n * 256 + t] = lv;
}

// layer 1: elu epilogue, fp32 out (consumed by elr2 + aggH gathers)

__global__ __launch_bounds__(256) void agg_kernel(const float* __restrict__ z,
                                                  const float* __restrict__ el,
                                                  const float* __restrict__ er,
                                                  const int* __restrict__ offs,
                                                  const int* __restrict__ psrc,
                                                  const float* __restrict__ bias,
                                                  float* __restrict__ out) {
    int n = blockIdx.x;
    int t = threadIdx.x;
    int h = t >> 6;
    __shared__ float p_lds[64][4];
    __shared__ int src_lds[64];
    __shared__ float den_lds[4];
    if (t < 4) den_lds[t] = 0.f;
    int beg = offs[n], end = offs[n + 1];
    float acc = 0.f;
    int e_local = t >> 2, hh = t & 3;
    float er_n = er[n * 4 + hh];
    for (int base = beg; base < end; base += 64) {
        int cnt = min(64, end - base);
        __syncthreads();
        if (e_local < cnt) {
            int s = psrc[base + e_local];
            if (hh == 0) src_lds[e_local] = s;
            float sc = el[s * 4 + hh] + er_n;
            sc = (sc > 0.f) ? sc : 0.2f * sc;
            float p = __expf(sc);
            p_lds[e_local][hh] = p;
            atomicAdd(&den_lds[hh], p);
        }
        __syncthreads();
        for (int e = 0; e < cnt; ++e) {
            acc += p_lds[e][h] * z[(size_t)src_lds[e] * 256 + t];
        }
    }
    __syncthreads();
    float o = acc / fmaxf(den_lds[h], 1e-9f) + bias[t];
    out[(size_t)n * 256 + t] = (o > 0.f) ? o : (__expf(o) - 1.f);
}

// layer-2 aggregation of h1 -> bf16 hi/lo row-major [N,1024] (consumed only by fin GEMM)

__global__ __launch_bounds__(256) void aggH_bf_kernel(const float* __restrict__ h1,
                                                      const float* __restrict__ el,
                                                      const float* __restrict__ er,
                                                      const int* __restrict__ offs,
                                                      const int* __restrict__ psrc,
                                                      short* __restrict__ ohi,
                                                      short* __restrict__ olo) {
    int n = blockIdx.x, t = threadIdx.x;
    __shared__ float p_lds[64][4];
    __shared__ int src_lds[64];
    __shared__ float den_lds[4];
    if (t < 4) den_lds[t] = 0.f;
    int beg = offs[n], end = offs[n + 1];
    float a0 = 0.f, a1 = 0.f, a2 = 0.f, a3 = 0.f;
    int e_local = t >> 2, hh = t & 3;
    float er_n = er[n * 4 + hh];
    for (int base = beg; base < end; base += 64) {
        int cnt = min(64, end - base);
        __syncthreads();
        if (e_local < cnt) {
            int s = psrc[base + e_local];
            if (hh == 0) src_lds[e_local] = s;
            float sc = el[s * 4 + hh] + er_n;
            sc = (sc > 0.f) ? sc : 0.2f * sc;
            float p = __expf(sc);
            p_lds[e_local][hh] = p;
            atomicAdd(&den_lds[hh], p);
        }
        __syncthreads();
        for (int e = 0; e < cnt; ++e) {
            float v = h1[(size_t)src_lds[e] * 256 + t];
            a0 += p_lds[e][0] * v;
            a1 += p_lds[e][1] * v;
            a2 += p_lds[e][2] * v;
            a3 += p_lds[e][3] * v;
        }
    }
    __syncthreads();
    float vals[4];
    vals[0] = a0 / fmaxf(den_lds[0], 1e-9f);
    vals[1] = a1 / fmaxf(den_lds[1], 1e-9f);
    vals[2] = a2 / fmaxf(den_lds[2], 1e-9f);
    vals[3] = a3 / fmaxf(den_lds[3], 1e-9f);
    size_t base_o = (size_t)n * 1024 + t;
#pragma unroll
    for (int h = 0; h < 4; ++h) {
        short hv, lv;
        split1(vals[h], hv, lv);
        ohi[base_o + h * 256] = hv;
        olo[base_o + h * 256] = lv;
    }
}

// ---------------- launch ----------------

extern "C" void kernel_launch(void* const* d_in, const int* in_sizes, int n_in,
                              void* d_out, int out_size, void* d_ws, size_t ws_size,
                              hipStream_t stream) {
    const float* feat = (const float*)d_in[0];
    const float* W0 = (const float*)d_in[1];
    const float* al0 = (const float*)d_in[2];
    const float* ar0 = (const float*)d_in[3];
    const float* b0 = (const float*)d_in[4];
    const float* W1 = (const float*)d_in[5];
    const float* al1 = (const float*)d_in[6];
    const float* ar1 = (const float*)d_in[7];
    const float* b1 = (const float*)d_in[8];
    const float* W2 = (const float*)d_in[9];
    const float* al2 = (const float*)d_in[10];
    const float* ar2 = (const float*)d_in[11];
    const float* b2 = (const float*)d_in[12];
    const int* src = (const int*)d_in[13];
    const int* dst = (const int*)d_in[14];
    float* out = (float*)d_out;

    // ---- workspace layout (~262.5 MB), time-multiplexed big slots ----
    // slotA (50000*1024 floats = 204.8 MB):
    //   layers 0/1: z (fp32 [N,256], first 51.2 MB) + featHL (at +51.2 MB)
    //   layer 2:    Ahi/Alo ([N,1024] bf16 each, whole slot)
    float* slotA = (float*)d_ws;
    float* z = slotA;                                     // [N,256] fp32
    short* feathi = (short*)(slotA + (size_t)NN * 256);   // 50000*128 shorts
    short* featlo = feathi + (size_t)NN * 128;
    short* Ahi = (short*)slotA;                           // [N,1024] shorts
    short* Alo = Ahi + (size_t)NN * 1024;
    // slotB (50000*256 floats = 51.2 MB): h0 hi/lo, then h1 fp32
    float* slotB = slotA + (size_t)NN * 1024;
    short* h0hi = (short*)slotB;                          // 50000*256 shorts
    short* h0lo = h0hi + (size_t)NN * 256;
    float* h1 = slotB;                                    // [N,256] fp32
    float* el = slotB + (size_t)NN * 256;                 // 200000
    float* er = el + (size_t)NN * NH_HEADS;               // 200000
    int* deg = (int*)(er + (size_t)NN * NH_HEADS);        // 50000
    int* offs = deg + NN;                                 // 50001 (+1 pad)
    int* cursor = offs + NN + 2;                          // 50000
    int* bsums = cursor + NN;                             // 256
    int* boffs = bsums + 256;                             // 256
    int* psrc = boffs + 256;                              // 800000 (+2 pad)
    short* Bh = (short*)(psrc + NE + 2);                  // 262144 shorts
    short* Bl = Bh + 262144;                              // 262144 shorts
    float* val = (float*)(Bl + 262144);                   // 1024
    float* var_ = val + 1024;                             // 1024

    // ---- CSR build (by dst) ----
    hipMemsetAsync(deg, 0, NN * sizeof(int), stream);
    hist_kernel<<<(NE + 255) / 256, 256, 0, stream>>>(dst, deg, NE);
    int nb = (NN + 255) / 256;
    scan_block_kernel<<<nb, 256, 0, stream>>>(deg, offs, bsums, NN);
    scan_sums_kernel<<<1, 256, 0, stream>>>(bsums, boffs, nb);
    add_offs_kernel<<<nb, 256, 0, stream>>>(offs, boffs, cursor, NN, NE);
    scatter_kernel<<<(NE + 255) / 256, 256, 0, stream>>>(src, dst, cursor, psrc, NE);

    int mb64 = (NN + 63) / 64; // 782

    // ---- layer 0: 128 -> 4x64, elu ----
    splitA_rm<<<(NN * 128 / 8 + 255) / 256, 256, 0, stream>>>(feat, feathi, featlo, NN * 128 / 8);
    splitB_kernel<<<(4096 + 255) / 256, 256, 0, stream>>>(W0, Bh, Bl, 128, 256);
    gemm_n256s<<<mb64, 256, 0, stream>>>(feathi, featlo, Bh, Bl, nullptr, z, NN, 128);
    elr_kernel<<<(NN * NH_HEADS) / 4, 256, 0, stream>>>(z, al0, ar0, el, er, NN * NH_HEADS, 64);
    agg_bf_kernel<<<NN, 256, 0, stream>>>(z, el, er, offs, psrc, b0, h0hi, h0lo);

    // ---- layer 1: 256 -> 4x64, elu ----
    splitB_kernel<<<(8192 + 255) / 256, 256, 0, stream>>>(W1, Bh, Bl, 256, 256);
    gemm_n256s<<<mb64, 256, 0, stream>>>(h0hi, h0lo, Bh, Bl, nullptr, z, NN, 256);
    elr_kernel<<<(NN * NH_HEADS) / 4, 256, 0, stream>>>(z, al1, ar1, el, er, NN * NH_HEADS, 64);
    agg_kernel<<<NN, 256, 0, stream>>>(z, el, er, offs, psrc, b1, h1);

    // ---- layer 2 (restructured): aggregate h1, then project ----
    proj_av_kernel<<<256, 256, 0, stream>>>(W2, al2, ar2, val, var_);
    elr2_kernel<<<NN, 256, 0, stream>>>(h1, val, var_, el, er);
    aggH_bf_kernel<<<NN, 256, 0, stream>>>(h1, el, er, offs, psrc, Ahi, Alo);
    splitB2_kernel<<<(32768 + 255) / 256, 256, 0, stream>>>(W2, Bh, Bl);
    gemm_n256s<<<mb64, 256, 0, stream>>>(Ahi, Alo, Bh, Bl, b2, out, NN, 1024);
}

// Round 7
// 881.091 us; speedup vs baseline: 1.0883x; 1.0883x over previous
//
#include <hip/hip_runtime.h>
#include <hip/hip_bf16.h>

// GAT: 3 layers. N=50000 nodes, E=800000 edges, H=4 heads.
// R7: GEMM = m97-style 2-barrier K-loop. A is bf16 hi/lo row-major from
// producers; staged to LDS via async global_load_lds (16B, no VGPR trip,
// no cvt), shared by all 4 waves. B frag-order register loads (L2-hit).

#define NN 50000
#define NE 800000
#define NH_HEADS 4

typedef __attribute__((ext_vector_type(8))) short short8;
typedef __attribute__((ext_vector_type(4))) float floatx4;

__device__ inline float bf2f(short s) {
    union { unsigned u; float f; } v; v.u = ((unsigned)(unsigned short)s) << 16;
    return v.f;
}
__device__ inline short f2bf_rne(float x) {
    union { float f; unsigned u; } v; v.f = x;
    unsigned r = v.u + 0x7fff + ((v.u >> 16) & 1);
    return (short)(r >> 16);
}
// truncation hi/lo split: hi = trunc16(x), lo = trunc16(x - hi)
__device__ inline void split1(float x, short& h, short& l) {
    union { float f; unsigned u; } v; v.f = x;
    h = (short)(v.u >> 16);
    union { float f; unsigned u; } rv; rv.f = v.f - bf2f(h);
    l = (short)(rv.u >> 16);
}

// async 16B/lane global->LDS; lds base must be wave-uniform (dest = base + lane*16)
__device__ inline void load_lds16(const short* g, short* l) {
    __builtin_amdgcn_global_load_lds(
        (const __attribute__((address_space(1))) void*)g,
        (__attribute__((address_space(3))) void*)l, 16, 0, 0);
}

// ---------------- CSR build ----------------

__global__ void hist_kernel(const int* __restrict__ dst, int* __restrict__ deg, int E) {
    int e = blockIdx.x * 256 + threadIdx.x;
    if (e < E) atomicAdd(&deg[dst[e]], 1);
}

__global__ void scan_block_kernel(const int* __restrict__ deg, int* __restrict__ offs,
                                  int* __restrict__ bsums, int n) {
    __shared__ int s[256];
    int tid = threadIdx.x;
    int i = blockIdx.x * 256 + tid;
    int v = (i < n) ? deg[i] : 0;
    s[tid] = v;
    __syncthreads();
    for (int off = 1; off < 256; off <<= 1) {
        int x = (tid >= off) ? s[tid - off] : 0;
        __syncthreads();
        s[tid] += x;
        __syncthreads();
    }
    if (i < n) offs[i] = s[tid] - v;
    if (tid == 255) bsums[blockIdx.x] = s[255];
}

__global__ void scan_sums_kernel(const int* __restrict__ bsums, int* __restrict__ boffs, int nb) {
    __shared__ int s[256];
    int tid = threadIdx.x;
    int v = (tid < nb) ? bsums[tid] : 0;
    s[tid] = v;
    __syncthreads();
    for (int off = 1; off < 256; off <<= 1) {
        int x = (tid >= off) ? s[tid - off] : 0;
        __syncthreads();
        s[tid] += x;
        __syncthreads();
    }
    boffs[tid] = s[tid] - v;
}

__global__ void add_offs_kernel(int* __restrict__ offs, const int* __restrict__ boffs,
                                int* __restrict__ cursor, int n, int total) {
    int i = blockIdx.x * 256 + threadIdx.x;
    if (i < n) {
        int o = offs[i] + boffs[blockIdx.x];
        offs[i] = o;
        cursor[i] = o;
    }
    if (i == 0) offs[n] = total;
}

__global__ void scatter_kernel(const int* __restrict__ src, const int* __restrict__ dst,
                               int* __restrict__ cursor, int* __restrict__ psrc, int E) {
    int e = blockIdx.x * 256 + threadIdx.x;
    if (e < E) {
        int p = atomicAdd(&cursor[dst[e]], 1);
        psrc[p] = src[e];
    }
}

// ---------------- A (row-major fp32) -> row-major bf16 hi/lo ----------------

__global__ __launch_bounds__(256) void splitA_rm(const float* __restrict__ A,
                                                 short* __restrict__ hi,
                                                 short* __restrict__ lo,
                                                 int total8) {
    int tid = blockIdx.x * 256 + threadIdx.x;
    if (tid >= total8) return;
    const float* p = A + (size_t)tid * 8;
    float4 x0 = ((const float4*)p)[0];
    float4 x1 = ((const float4*)p)[1];
    float xs[8] = {x0.x, x0.y, x0.z, x0.w, x1.x, x1.y, x1.z, x1.w};
    short8 hv, lv;
#pragma unroll
    for (int j = 0; j < 8; ++j) { short h, l; split1(xs[j], h, l); hv[j] = h; lv[j] = l; }
    ((short8*)hi)[tid] = hv;
    ((short8*)lo)[tid] = lv;
}

// ---------------- B -> bf16 hi/lo in MFMA B-fragment order ----------------
// offset (short8) = (c*(N/16)+g)*64 + lane ; lane=(n&15)+16*((k&31)>>3), j=k&7

__global__ __launch_bounds__(256) void splitB_kernel(const float* __restrict__ B,
                                                     short* __restrict__ hi,
                                                     short* __restrict__ lo,
                                                     int K, int N) {
    int tid = blockIdx.x * 256 + threadIdx.x;
    int NG = N >> 4;
    int total = (K >> 5) * NG * 64;
    if (tid >= total) return;
    int lane = tid & 63;
    int rc = tid >> 6;
    int g = rc % NG, c = rc / NG;
    int n = g * 16 + (lane & 15);
    int k = c * 32 + (lane >> 4) * 8;
    short8 hv, lv;
#pragma unroll
    for (int j = 0; j < 8; ++j) {
        float x = B[(size_t)(k + j) * N + n];
        short h = f2bf_rne(x);
        hv[j] = h;
        lv[j] = f2bf_rne(x - bf2f(h));
    }
    ((short8*)hi)[tid] = hv;
    ((short8*)lo)[tid] = lv;
}

// permuted-W2: Bp[h*256+k, c] = W2[k, h*256+c]; K=1024, N=256
__global__ __launch_bounds__(256) void splitB2_kernel(const float* __restrict__ W2,
                                                      short* __restrict__ hi,
                                                      short* __restrict__ lo) {
    int tid = blockIdx.x * 256 + threadIdx.x;
    const int NG = 16;
    int total = (1024 >> 5) * NG * 64;   // 32768
    if (tid >= total) return;
    int lane = tid & 63;
    int rc = tid >> 6;
    int g = rc % NG, c = rc / NG;
    int n = g * 16 + (lane & 15);
    int kk = c * 32 + (lane >> 4) * 8;
    short8 hv, lv;
#pragma unroll
    for (int j = 0; j < 8; ++j) {
        int kg = kk + j;
        int h = kg >> 8, k = kg & 255;
        float x = W2[(size_t)k * 1024 + h * 256 + n];
        short hb = f2bf_rne(x);
        hv[j] = hb;
        lv[j] = f2bf_rne(x - bf2f(hb));
    }
    ((short8*)hi)[tid] = hv;
    ((short8*)lo)[tid] = lv;
}

// ---------------- MFMA GEMM, N=256, A via async LDS staging ----------------
// block: 64 rows x 256 cols; wave w owns rows [bm,bm+64) x cols [w*64,(w+1)*64).
// Staging: wave w stages m-tile w (16 rows x 32 k): lane -> row (lane&15),
// k-octet (lane>>4); LDS dest = tile base + lane*16 (fragment order).

__device__ inline floatx4 mfma16(short8 a, short8 b, floatx4 c) {
    return __builtin_amdgcn_mfma_f32_16x16x32_bf16(a, b, c, 0, 0, 0);
}

__global__ __launch_bounds__(256) void gemm_n256l(const short* __restrict__ Ahi,
                                                  const short* __restrict__ Alo,
                                                  const short* __restrict__ Bh,
                                                  const short* __restrict__ Bl,
                                                  const float* __restrict__ bias4,
                                                  float* __restrict__ C,
                                                  int M, int K) {
    int KC = K >> 5;
    __shared__ short AhL[2048];   // 4 m-tiles x 64 lanes x 8 shorts = 4 KB
    __shared__ short AlL[2048];
    int t = threadIdx.x;
    int lane = t & 63;
    int w = t >> 6;
    int bm = blockIdx.x * 64;
    int g0 = w * 4;
    const short8* pBh = (const short8*)Bh;
    const short8* pBl = (const short8*)Bl;

    floatx4 acc[4][4] = {};

    // staging source for this lane (m-tile w)
    int row = bm + (w << 4) + (lane & 15);
    if (row >= M) row = M - 1;                    // clamp: junk rows never stored
    const short* gh = Ahi + (size_t)row * K + ((lane >> 4) << 3);
    const short* gl = Alo + (size_t)row * K + ((lane >> 4) << 3);
    short* lh = AhL + w * 512;                    // wave-uniform LDS base
    short* ll = AlL + w * 512;

    for (int c = 0; c < KC; ++c) {
        // async A stage (chunk c) + B frag loads (chunk c)
        load_lds16(gh + (size_t)c * 32, lh);
        load_lds16(gl + (size_t)c * 32, ll);
        short8 bh[4], bl[4];
#pragma unroll
        for (int g = 0; g < 4; ++g) {
            bh[g] = pBh[((size_t)c * (256 / 16) + g0 + g) * 64 + lane];
            bl[g] = pBl[((size_t)c * (256 / 16) + g0 + g) * 64 + lane];
        }
        __syncthreads();   // drains vmcnt: LDS staged, B regs ready
#pragma unroll
        for (int mt = 0; mt < 4; ++mt) {
            short8 ah = *(const short8*)(AhL + mt * 512 + lane * 8);
            short8 al = *(const short8*)(AlL + mt * 512 + lane * 8);
#pragma unroll
            for (int g = 0; g < 4; ++g) {
                acc[mt][g] = mfma16(ah, bh[g], acc[mt][g]);
                acc[mt][g] = mfma16(al, bh[g], acc[mt][g]);
                acc[mt][g] = mfma16(ah, bl[g], acc[mt][g]);
            }
        }
        __syncthreads();   // all LDS reads done before next overwrite
    }

    // C/D layout: col = lane&15, row = (lane>>4)*4 + reg
    int rowb = bm + (lane >> 4) * 4;
    int colb = w * 64 + (lane & 15);
#pragma unroll
    for (int mt = 0; mt < 4; ++mt) {
#pragma unroll
        for (int r = 0; r < 4; ++r) {
            int rr = rowb + mt * 16 + r;
            if (rr < M) {
#pragma unroll
                for (int g = 0; g < 4; ++g) {
                    int col = colb + g * 16;
                    float v = acc[mt][g][r];
                    if (bias4) {
                        v = 0.25f * (v + bias4[col] + bias4[col + 256] +
                                     bias4[col + 512] + bias4[col + 768]);
                    }
                    C[(size_t)rr * 256 + col] = v;
                }
            }
        }
    }
}

// ---------------- attention score parts ----------------

__global__ __launch_bounds__(256) void elr_kernel(const float* __restrict__ z,
                                                  const float* __restrict__ al,
                                                  const float* __restrict__ ar,
                                                  float* __restrict__ el,
                                                  float* __restrict__ er,
                                                  int NH, int F) {
    int gid = blockIdx.x * 256 + threadIdx.x;
    int w = gid >> 6;
    int lane = threadIdx.x & 63;
    if (w >= NH) return;
    int n = w >> 2, h = w & 3;
    const float* zr = z + (size_t)n * (4 * F) + h * F;
    const float* alr = al + h * F;
    const float* arr = ar + h * F;
    float se = 0.f, sr = 0.f;
    for (int f = lane; f < F; f += 64) {
        float zv = zr[f];
        se += zv * alr[f];
        sr += zv * arr[f];
    }
#pragma unroll
    for (int off = 32; off > 0; off >>= 1) {
        se += __shfl_down(se, off);
        sr += __shfl_down(sr, off);
    }
    if (lane == 0) { el[w] = se; er[w] = sr; }
}

// val[h*256+k] = sum_j W2[k,h*256+j]*al2[h,j] ; var likewise with ar2
__global__ __launch_bounds__(256) void proj_av_kernel(const float* __restrict__ W2,
                                                      const float* __restrict__ al2,
                                                      const float* __restrict__ ar2,
                                                      float* __restrict__ val,
                                                      float* __restrict__ var_) {
    int gid = blockIdx.x * 256 + threadIdx.x;
    int w = gid >> 6;
    int lane = threadIdx.x & 63;
    if (w >= 1024) return;
    int h = w >> 8, k = w & 255;
    const float* wrow = W2 + (size_t)k * 1024 + h * 256;
    const float* ap = al2 + h * 256;
    const float* rp = ar2 + h * 256;
    float sv = 0.f, sr = 0.f;
    for (int j = lane; j < 256; j += 64) {
        float x = wrow[j];
        sv += x * ap[j];
        sr += x * rp[j];
    }
#pragma unroll
    for (int off = 32; off > 0; off >>= 1) {
        sv += __shfl_down(sv, off);
        sr += __shfl_down(sr, off);
    }
    if (lane == 0) { val[w] = sv; var_[w] = sr; }
}

// el[n,h] = h1[n,:]·val[h,:], er likewise
__global__ __launch_bounds__(256) void elr2_kernel(const float* __restrict__ h1,
                                                   const float* __restrict__ val,
                                                   const float* __restrict__ var_,
                                                   float* __restrict__ el,
                                                   float* __restrict__ er) {
    int gid = blockIdx.x * 256 + threadIdx.x;
    int w = gid >> 6;
    int lane = threadIdx.x & 63;
    if (w >= NN * 4) return;
    int n = w >> 2, h = w & 3;
    const float* hr = h1 + (size_t)n * 256;
    const float* vp = val + h * 256;
    const float* rp = var_ + h * 256;
    float se = 0.f, sr = 0.f;
    for (int k = lane; k < 256; k += 64) {
        float x = hr[k];
        se += x * vp[k];
        sr += x * rp[k];
    }
#pragma unroll
    for (int off = 32; off > 0; off >>= 1) {
        se += __shfl_down(se, off);
        sr += __shfl_down(sr, off);
    }
    if (lane == 0) { el[w] = se; er[w] = sr; }
}

// ---------------- aggregation ----------------
// layer 0: elu epilogue, writes bf16 hi/lo row-major (consumed only by L1 GEMM)

__global__ __launch_bounds__(256) void agg_bf_kernel(const float* __restrict__ z,
                                                     const float* __restrict__ el,
                                                     const float* __restrict__ er,
                                                     const int* __restrict__ offs,
                                                     const int* __restrict__ psrc,
                                                     const float* __restrict__ bias,
                                                     short* __restrict__ ohi,
                                                     short* __restrict__ olo) {
    int n = blockIdx.x;
    int t = threadIdx.x;
    int h = t >> 6;
    __shared__ float p_lds[64][4];
    __shared__ int src_lds[64];
    __shared__ float den_lds[4];
    if (t < 4) den_lds[t] = 0.f;
    int beg = offs[n], end = offs[n + 1];
    float acc = 0.f;
    int e_local = t >> 2, hh = t & 3;
    float er_n = er[n * 4 + hh];
    for (int base = beg; base < end; base += 64) {
        int cnt = min(64, end - base);
        __syncthreads();
        if (e_local < cnt) {
            int s = psrc[base + e_local];
            if (hh == 0) src_lds[e_local] = s;
            float sc = el[s * 4 + hh] + er_n;
            sc = (sc > 0.f) ? sc : 0.2f * sc;
            float p = __expf(sc);
            p_lds[e_local][hh] = p;
            atomicAdd(&den_lds[hh], p);
        }
        __syncthreads();
        for (int e = 0; e < cnt; ++e) {
            acc += p_lds[e][h] * z[(size_t)src_lds[e] * 256 + t];
        }
    }
    __syncthreads();
    float o = acc / fmaxf(den_lds[h], 1e-9f) + bias[t];
    o = (o > 0.f) ? o : (__expf(o) - 1.f);
    short hv, lv;
    split1(o, hv, lv);
    ohi[(size_t)n * 256 + t] = hv;
    olo[(size_t)n * 256 + t] = lv;
}

// layer 1: elu epilogue, fp32 out (consumed by elr2 + aggH gathers)

__global__ __launch_bounds__(256) void agg_kernel(const float* __restrict__ z,
                                                  const float* __restrict__ el,
                                                  const float* __restrict__ er,
                                                  const int* __restrict__ offs,
                                                  const int* __restrict__ psrc,
                                                  const float* __restrict__ bias,
                                                  float* __restrict__ out) {
    int n = blockIdx.x;
    int t = threadIdx.x;
    int h = t >> 6;
    __shared__ float p_lds[64][4];
    __shared__ int src_lds[64];
    __shared__ float den_lds[4];
    if (t < 4) den_lds[t] = 0.f;
    int beg = offs[n], end = offs[n + 1];
    float acc = 0.f;
    int e_local = t >> 2, hh = t & 3;
    float er_n = er[n * 4 + hh];
    for (int base = beg; base < end; base += 64) {
        int cnt = min(64, end - base);
        __syncthreads();
        if (e_local < cnt) {
            int s = psrc[base + e_local];
            if (hh == 0) src_lds[e_local] = s;
            float sc = el[s * 4 + hh] + er_n;
            sc = (sc > 0.f) ? sc : 0.2f * sc;
            float p = __expf(sc);
            p_lds[e_local][hh] = p;
            atomicAdd(&den_lds[hh], p);
        }
        __syncthreads();
        for (int e = 0; e < cnt; ++e) {
            acc += p_lds[e][h] * z[(size_t)src_lds[e] * 256 + t];
        }
    }
    __syncthreads();
    float o = acc / fmaxf(den_lds[h], 1e-9f) + bias[t];
    out[(size_t)n * 256 + t] = (o > 0.f) ? o : (__expf(o) - 1.f);
}

// layer-2 aggregation of h1 -> bf16 hi/lo row-major [N,1024] (consumed only by fin GEMM)

__global__ __launch_bounds__(256) void aggH_bf_kernel(const float* __restrict__ h1,
                                                      const float* __restrict__ el,
                                                      const float* __restrict__ er,
                                                      const int* __restrict__ offs,
                                                      const int* __restrict__ psrc,
                                                      short* __restrict__ ohi,
                                                      short* __restrict__ olo) {
    int n = blockIdx.x, t = threadIdx.x;
    __shared__ float p_lds[64][4];
    __shared__ int src_lds[64];
    __shared__ float den_lds[4];
    if (t < 4) den_lds[t] = 0.f;
    int beg = offs[n], end = offs[n + 1];
    float a0 = 0.f, a1 = 0.f, a2 = 0.f, a3 = 0.f;
    int e_local = t >> 2, hh = t & 3;
    float er_n = er[n * 4 + hh];
    for (int base = beg; base < end; base += 64) {
        int cnt = min(64, end - base);
        __syncthreads();
        if (e_local < cnt) {
            int s = psrc[base + e_local];
            if (hh == 0) src_lds[e_local] = s;
            float sc = el[s * 4 + hh] + er_n;
            sc = (sc > 0.f) ? sc : 0.2f * sc;
            float p = __expf(sc);
            p_lds[e_local][hh] = p;
            atomicAdd(&den_lds[hh], p);
        }
        __syncthreads();
        for (int e = 0; e < cnt; ++e) {
            float v = h1[(size_t)src_lds[e] * 256 + t];
            a0 += p_lds[e][0] * v;
            a1 += p_lds[e][1] * v;
            a2 += p_lds[e][2] * v;
            a3 += p_lds[e][3] * v;
        }
    }
    __syncthreads();
    float vals[4];
    vals[0] = a0 / fmaxf(den_lds[0], 1e-9f);
    vals[1] = a1 / fmaxf(den_lds[1], 1e-9f);
    vals[2] = a2 / fmaxf(den_lds[2], 1e-9f);
    vals[3] = a3 / fmaxf(den_lds[3], 1e-9f);
    size_t base_o = (size_t)n * 1024 + t;
#pragma unroll
    for (int h = 0; h < 4; ++h) {
        short hv, lv;
        split1(vals[h], hv, lv);
        ohi[base_o + h * 256] = hv;
        olo[base_o + h * 256] = lv;
    }
}

// ---------------- launch ----------------

extern "C" void kernel_launch(void* const* d_in, const int* in_sizes, int n_in,
                              void* d_out, int out_size, void* d_ws, size_t ws_size,
                              hipStream_t stream) {
    const float* feat = (const float*)d_in[0];
    const float* W0 = (const float*)d_in[1];
    const float* al0 = (const float*)d_in[2];
    const float* ar0 = (const float*)d_in[3];
    const float* b0 = (const float*)d_in[4];
    const float* W1 = (const float*)d_in[5];
    const float* al1 = (const float*)d_in[6];
    const float* ar1 = (const float*)d_in[7];
    const float* b1 = (const float*)d_in[8];
    const float* W2 = (const float*)d_in[9];
    const float* al2 = (const float*)d_in[10];
    const float* ar2 = (const float*)d_in[11];
    const float* b2 = (const float*)d_in[12];
    const int* src = (const int*)d_in[13];
    const int* dst = (const int*)d_in[14];
    float* out = (float*)d_out;

    // ---- workspace layout (~262.5 MB), time-multiplexed big slots ----
    float* slotA = (float*)d_ws;
    float* z = slotA;                                     // [N,256] fp32
    short* feathi = (short*)(slotA + (size_t)NN * 256);   // 50000*128 shorts
    short* featlo = feathi + (size_t)NN * 128;
    short* Ahi = (short*)slotA;                           // [N,1024] shorts (layer 2)
    short* Alo = Ahi + (size_t)NN * 1024;
    float* slotB = slotA + (size_t)NN * 1024;
    short* h0hi = (short*)slotB;                          // 50000*256 shorts
    short* h0lo = h0hi + (size_t)NN * 256;
    float* h1 = slotB;                                    // [N,256] fp32 (layer 2)
    float* el = slotB + (size_t)NN * 256;                 // 200000
    float* er = el + (size_t)NN * NH_HEADS;               // 200000
    int* deg = (int*)(er + (size_t)NN * NH_HEADS);        // 50000
    int* offs = deg + NN;                                 // 50001 (+1 pad)
    int* cursor = offs + NN + 2;                          // 50000
    int* bsums = cursor + NN;                             // 256
    int* boffs = bsums + 256;                             // 256
    int* psrc = boffs + 256;                              // 800000 (+2 pad)
    short* Bh = (short*)(psrc + NE + 2);                  // 262144 shorts
    short* Bl = Bh + 262144;                              // 262144 shorts
    float* val = (float*)(Bl + 262144);                   // 1024
    float* var_ = val + 1024;                             // 1024

    // ---- CSR build (by dst) ----
    hipMemsetAsync(deg, 0, NN * sizeof(int), stream);
    hist_kernel<<<(NE + 255) / 256, 256, 0, stream>>>(dst, deg, NE);
    int nb = (NN + 255) / 256;
    scan_block_kernel<<<nb, 256, 0, stream>>>(deg, offs, bsums, NN);
    scan_sums_kernel<<<1, 256, 0, stream>>>(bsums, boffs, nb);
    add_offs_kernel<<<nb, 256, 0, stream>>>(offs, boffs, cursor, NN, NE);
    scatter_kernel<<<(NE + 255) / 256, 256, 0, stream>>>(src, dst, cursor, psrc, NE);

    int mb64 = (NN + 63) / 64; // 782

    // ---- layer 0: 128 -> 4x64, elu ----
    splitA_rm<<<(NN * 128 / 8 + 255) / 256, 256, 0, stream>>>(feat, feathi, featlo, NN * 128 / 8);
    splitB_kernel<<<(4096 + 255) / 256, 256, 0, stream>>>(W0, Bh, Bl, 128, 256);
    gemm_n256l<<<mb64, 256, 0, stream>>>(feathi, featlo, Bh, Bl, nullptr, z, NN, 128);
    elr_kernel<<<(NN * NH_HEADS) / 4, 256, 0, stream>>>(z, al0, ar0, el, er, NN * NH_HEADS, 64);
    agg_bf_kernel<<<NN, 256, 0, stream>>>(z, el, er, offs, psrc, b0, h0hi, h0lo);

    // ---- layer 1: 256 -> 4x64, elu ----
    splitB_kernel<<<(8192 + 255) / 256, 256, 0, stream>>>(W1, Bh, Bl, 256, 256);
    gemm_n256l<<<mb64, 256, 0, stream>>>(h0hi, h0lo, Bh, Bl, nullptr, z, NN, 256);
    elr_kernel<<<(NN * NH_HEADS) / 4, 256, 0, stream>>>(z, al1, ar1, el, er, NN * NH_HEADS, 64);
    agg_kernel<<<NN, 256, 0, stream>>>(z, el, er, offs, psrc, b1, h1);

    // ---- layer 2 (restructured): aggregate h1, then project ----
    proj_av_kernel<<<256, 256, 0, stream>>>(W2, al2, ar2, val, var_);
    elr2_kernel<<<NN, 256, 0, stream>>>(h1, val, var_, el, er);
    aggH_bf_kernel<<<NN, 256, 0, stream>>>(h1, el, er, offs, psrc, Ahi, Alo);
    splitB2_kernel<<<(32768 + 255) / 256, 256, 0, stream>>>(W2, Bh, Bl);
    gemm_n256l<<<mb64, 256, 0, stream>>>(Ahi, Alo, Bh, Bl, b2, out, NN, 1024);
}